// Round 11
// baseline (522.020 us; speedup 1.0000x reference)
//
#include <hip/hip_runtime.h>
#include <cstdint>
#include <cstddef>

typedef __bf16 bf16;
typedef __attribute__((ext_vector_type(4))) float f32x4;
typedef __attribute__((ext_vector_type(8))) __bf16 bf16x8;
typedef __attribute__((ext_vector_type(4))) __bf16 bf16x4;

static __device__ __forceinline__ f32x4 mfma16(bf16x8 a, bf16x8 b, f32x4 c) {
    return __builtin_amdgcn_mfma_f32_16x16x32_bf16(a, b, c, 0, 0, 0);
}

#define GLOAD_LDS16(gsrc, ldst)                                              \
    __builtin_amdgcn_global_load_lds(                                        \
        (const __attribute__((address_space(1))) void*)(gsrc),               \
        (__attribute__((address_space(3))) void*)(ldst), 16, 0, 0)

// ---------------------------------------------------------------------------
// Weight transpose + cast: Wt[n*K + k] = bf16(W[k*N + n])
// ---------------------------------------------------------------------------
__global__ __launch_bounds__(256)
void transpose_cast(const float* __restrict__ W, bf16* __restrict__ Wt, int K, int N) {
    __shared__ float tile[32][33];
    const int n0 = blockIdx.x * 32, k0 = blockIdx.y * 32;
    const int tx = threadIdx.x & 31, ty = threadIdx.x >> 5;  // ty 0..7
    #pragma unroll
    for (int i = ty; i < 32; i += 8)
        tile[i][tx] = W[(size_t)(k0 + i) * N + n0 + tx];
    __syncthreads();
    #pragma unroll
    for (int i = ty; i < 32; i += 8)
        Wt[(size_t)(n0 + i) * K + k0 + tx] = (bf16)tile[tx][i];
}

// ---------------------------------------------------------------------------
// LayerNorm over 512 cols, fp32 in -> bf16 out. 1 wave per row, 4 rows/block.
// ---------------------------------------------------------------------------
__global__ __launch_bounds__(256)
void ln_kernel(const float* __restrict__ x, const float* __restrict__ g,
               const float* __restrict__ b, bf16* __restrict__ out) {
    const int row = blockIdx.x * 4 + (threadIdx.x >> 6);
    const int lane = threadIdx.x & 63;
    const float* p = x + (size_t)row * 512 + lane * 8;
    const float4 a0 = *(const float4*)p;
    const float4 a1 = *(const float4*)(p + 4);
    float vx[8] = {a0.x, a0.y, a0.z, a0.w, a1.x, a1.y, a1.z, a1.w};
    float s = 0.f, ss = 0.f;
    #pragma unroll
    for (int k = 0; k < 8; ++k) { s += vx[k]; ss += vx[k] * vx[k]; }
    #pragma unroll
    for (int m = 1; m < 64; m <<= 1) {
        s  += __shfl_xor(s, m);
        ss += __shfl_xor(ss, m);
    }
    const float mean = s * (1.0f / 512.0f);
    const float var  = ss * (1.0f / 512.0f) - mean * mean;
    const float inv  = rsqrtf(var + 1e-5f);
    const int c0 = lane * 8;
    const float4 g0 = *(const float4*)&g[c0], g1 = *(const float4*)&g[c0 + 4];
    const float4 b0 = *(const float4*)&b[c0], b1 = *(const float4*)&b[c0 + 4];
    const float gv[8] = {g0.x, g0.y, g0.z, g0.w, g1.x, g1.y, g1.z, g1.w};
    const float bv[8] = {b0.x, b0.y, b0.z, b0.w, b1.x, b1.y, b1.z, b1.w};
    bf16x8 o;
    #pragma unroll
    for (int k = 0; k < 8; ++k)
        o[k] = (bf16)((vx[k] - mean) * inv * gv[k] + bv[k]);
    *(bf16x8*)&out[(size_t)row * 512 + c0] = o;
}

// ---------------------------------------------------------------------------
// GEMM: C[M,N] = A[M,K] bf16 x Bt[N,K]^T bf16. 128x128 tile, BK=32,
// 8 waves (512 thr) in a 4Mx2N grid -> per-wave 32x64 output (acc[2][4],
// 32 VGPR). Wave rows are 64 bf16 = 128B = FULL cache lines (R10 showed the
// 32-col tile's 64B partial-line bf16 stores inflating WRITE_SIZE 64->82MB).
// __launch_bounds__(512,8): 32 waves/CU (verified occ ~74%). K template:
// pair-loop with #pragma unroll 8 -> K=512 fully unrolled, K=2048 unrolled
// 8 (R10's full 63-step unroll regressed FC2). Double-buffered 32KB linear
// LDS via global_load_lds(16B) + source slot swizzle, one barrier per
// K-step, XCD-chunked block swizzle. Vectorized full-line epilogues via
// per-wave [16][64] fp32 LDS bounce (+-16 XOR on scatter).
// EPI 0: bf16. EPI 1: +bias +res(fp32), fp32. EPI 2: +bias, GELU, bf16.
// ---------------------------------------------------------------------------
template <int EPI, int K>
__global__ __launch_bounds__(512, 8)
void gemm_bt(const bf16* __restrict__ A, const bf16* __restrict__ Bt,
             int N, const float* __restrict__ bias,
             const float* __restrict__ res, float* __restrict__ outf,
             bf16* __restrict__ outh) {
    __shared__ __align__(16) bf16 smem[16384];   // 32 KB
    auto lsA = [&](int buf) { return smem + buf * 4096; };
    auto lsB = [&](int buf) { return smem + 8192 + buf * 4096; };
    const int nx = gridDim.x;
    const int nwg = nx * gridDim.y;
    const int flat = blockIdx.y * nx + blockIdx.x;
    const int cpx = nwg >> 3;
    const int bswz = (flat & 7) * cpx + (flat >> 3);
    const int bn = bswz % nx, bm = bswz / nx;

    const int tid = threadIdx.x, lane = tid & 63, wv = tid >> 6;   // wv 0..7
    const int wr = wv & 3, wc = wv >> 2;        // 4M x 2N wave grid
    const int l15 = lane & 15, lg = lane >> 4;
    const size_t abase = (size_t)bm * 128 * K;
    const size_t bbase = (size_t)bn * 128 * K;
    // staging: wave wv stages 16-row chunk wv of A and of B (1 load each).
    const int sr = wv * 16 + (lane >> 2);        // global tile row
    const int ks = ((lane & 3) ^ ((sr >> 1) & 3)) * 8;  // swizzled k-offset
    const bf16* aSrc = &A[abase + (size_t)sr * K + ks];
    const bf16* bSrc = &Bt[bbase + (size_t)sr * K + ks];

    f32x4 acc[2][4] = {};

    auto stage = [&](int buf, int kt) {   // 2 loads/wave
        GLOAD_LDS16(aSrc + kt, lsA(buf) + wv * 512);
        GLOAD_LDS16(bSrc + kt, lsB(buf) + wv * 512);
    };
    auto compute = [&](int buf) {
        bf16x8 af[2], bfr[4];
        #pragma unroll
        for (int i = 0; i < 2; ++i) {
            const int r = wr * 32 + i * 16 + l15;
            af[i] = *(const bf16x8*)
                (lsA(buf) + r * 32 + ((lg ^ ((r >> 1) & 3)) * 8));
        }
        #pragma unroll
        for (int j = 0; j < 4; ++j) {
            const int r = wc * 64 + j * 16 + l15;
            bfr[j] = *(const bf16x8*)
                (lsB(buf) + r * 32 + ((lg ^ ((r >> 1) & 3)) * 8));
        }
        #pragma unroll
        for (int i = 0; i < 2; ++i)
            #pragma unroll
            for (int j = 0; j < 4; ++j)
                acc[i][j] = mfma16(af[i], bfr[j], acc[i][j]);
    };

    constexpr int NK = K >> 5;     // 16 or 64
    constexpr int NP = NK >> 1;    // pairs: 8 or 32
    stage(0, 0);
    __syncthreads();
    #pragma unroll 8
    for (int tp = 0; tp < NP; ++tp) {
        stage(1, (2 * tp + 1) * 32);
        compute(0);
        __syncthreads();
        if (2 * tp + 2 < NK) stage(0, (2 * tp + 2) * 32);
        compute(1);
        __syncthreads();           // last iter: doubles as pre-epilogue sync
    }

    // ---- vectorized full-line epilogue via per-wave LDS bounce ----
    // per-wave region: [16][64] fp32 (4KB x 8 waves = 32KB exactly).
    // scatter swizzle: col ^= ((row>>2)&1)*16  -> 2-way banks (free).
    float* lsW = (float*)smem + wv * 1024;
    const int orow = bm * 128 + wr * 32;
    const int ocol = bn * 128 + wc * 64;
    #pragma unroll
    for (int i = 0; i < 2; ++i) {
        #pragma unroll
        for (int r = 0; r < 4; ++r)
            #pragma unroll
            for (int j = 0; j < 4; ++j) {
                const int row = lg * 4 + r;
                const int col = (j * 16 + l15) ^ ((lg & 1) * 16);
                lsW[row * 64 + col] = acc[i][j][r];
            }
        __builtin_amdgcn_s_waitcnt(0);   // lgkmcnt(0): same-wave visibility
        if constexpr (EPI == 0 || EPI == 2) {
            // 2 passes x 8 rows; per row 8 lanes x 16B bf16 = 128B full line
            const int c8 = (lane & 7) * 8;
            #pragma unroll
            for (int p = 0; p < 2; ++p) {
                const int rw = p * 8 + (lane >> 3);
                const int cs = c8 ^ (((rw >> 2) & 1) * 16);
                const float4 v0 = *(const float4*)&lsW[rw * 64 + cs];
                const float4 v1 = *(const float4*)&lsW[rw * 64 + cs + 4];
                float vv[8] = {v0.x, v0.y, v0.z, v0.w, v1.x, v1.y, v1.z, v1.w};
                if constexpr (EPI == 2) {
                    const float4 bb0 = *(const float4*)&bias[ocol + c8];
                    const float4 bb1 = *(const float4*)&bias[ocol + c8 + 4];
                    const float bv[8] = {bb0.x, bb0.y, bb0.z, bb0.w,
                                         bb1.x, bb1.y, bb1.z, bb1.w};
                    #pragma unroll
                    for (int e = 0; e < 8; ++e) {
                        const float t = vv[e] + bv[e];
                        vv[e] = 0.5f * t * (1.0f + erff(t * 0.70710678118f));
                    }
                }
                bf16x8 o;
                #pragma unroll
                for (int e = 0; e < 8; ++e) o[e] = (bf16)vv[e];
                *(bf16x8*)&outh[(size_t)(orow + i * 16 + rw) * N + ocol + c8] = o;
            }
        } else {
            // 4 passes x 4 rows; per row 16 lanes x 16B fp32 = 256B full lines
            const int c4 = (lane & 15) * 4;
            const float4 bb = *(const float4*)&bias[ocol + c4];
            #pragma unroll
            for (int p = 0; p < 4; ++p) {
                const int rw = p * 4 + (lane >> 4);
                const int cs = c4 ^ (((rw >> 2) & 1) * 16);
                const size_t gro = (size_t)(orow + i * 16 + rw) * N + ocol + c4;
                float4 v = *(const float4*)&lsW[rw * 64 + cs];
                const float4 rr = *(const float4*)&res[gro];
                v.x += bb.x + rr.x; v.y += bb.y + rr.y;
                v.z += bb.z + rr.z; v.w += bb.w + rr.w;
                *(float4*)&outf[gro] = v;
            }
        }
    }
}

// ---------------------------------------------------------------------------
// Attention stats: block = (window w = bid>>2, head quad q = bid&3), one head
// per wave. Partial |QK^T + 0.1*rpe| sums -> Mraw4[w*4+q] (deterministic).
// ---------------------------------------------------------------------------
__global__ __launch_bounds__(256)
void attn_stats(const bf16* __restrict__ qkv, const float* __restrict__ rpe,
                float* __restrict__ Mraw4, int idx) {
    __shared__ float lsum[4];
    const int bid = blockIdx.x;
    const int w = bid >> 2;
    const int tid = threadIdx.x, lane = tid & 63, wv = tid >> 6;
    const int h = (bid & 3) * 4 + wv;
    const int l15 = lane & 15, lg = lane >> 4;
    const long gbase = (idx == 0) ? (long)w * 64 : ((long)(w >> 6) * 4096 + (w & 63));
    const long gstride = (idx == 0) ? 1 : 64;
    bf16x8 kf[4];
    #pragma unroll
    for (int i = 0; i < 4; ++i) {
        const long gs = gbase + (long)(i * 16 + l15) * gstride;
        kf[i] = *(const bf16x8*)&qkv[gs * 1536 + 512 + h * 32 + lg * 8];
    }
    const float* rh = rpe + h * 4096;
    float asum = 0.f;
    #pragma unroll
    for (int mi = 0; mi < 4; ++mi) {
        const long gs = gbase + (long)(mi * 16 + l15) * gstride;
        const bf16x8 qf = *(const bf16x8*)&qkv[gs * 1536 + h * 32 + lg * 8];
        f32x4 sc[4] = {};
        #pragma unroll
        for (int ni = 0; ni < 4; ++ni) sc[ni] = mfma16(qf, kf[ni], sc[ni]);
        #pragma unroll
        for (int r = 0; r < 4; ++r) {
            const int srow = mi * 16 + lg * 4 + r;
            #pragma unroll
            for (int ni = 0; ni < 4; ++ni)
                asum += fabsf(sc[ni][r] + 0.1f * rh[srow * 64 + ni * 16 + l15]);
        }
    }
    #pragma unroll
    for (int m = 1; m < 64; m <<= 1) asum += __shfl_xor(asum, m);
    if (lane == 0) lsum[wv] = asum;
    __syncthreads();
    if (tid == 0) Mraw4[bid] = lsum[0] + lsum[1] + lsum[2] + lsum[3];
}

// M[w] = max( (sum(Mraw4[w*4..+3])/65536) / max_w(...), 0.5 )
__global__ __launch_bounds__(256)
void mcalc(const float* __restrict__ Mraw4, float* __restrict__ Mv) {
    __shared__ float red[4];
    const int t = threadIdx.x, lane = t & 63;
    const float v = (Mraw4[t * 4] + Mraw4[t * 4 + 1] + Mraw4[t * 4 + 2] +
                     Mraw4[t * 4 + 3]) * (1.0f / 65536.0f);
    float m = v;
    #pragma unroll
    for (int msk = 1; msk < 64; msk <<= 1) m = fmaxf(m, __shfl_xor(m, msk));
    if (lane == 0) red[t >> 6] = m;
    __syncthreads();
    const float mm = fmaxf(fmaxf(red[0], red[1]), fmaxf(red[2], red[3]));
    Mv[t] = fmaxf(v / mm, 0.5f);
}

// ---------------------------------------------------------------------------
// Attention apply: block = (window, head quad), one head per wave.
// QK^T (MFMA) -> +0.1*rpe -> row L2-norm -> 1-cos -> *M -> P in swizzled LDS
// -> PV via MFMA with V^T in swizzled LDS -> unpartition + masked residual.
// ---------------------------------------------------------------------------
__global__ __launch_bounds__(256)
void attn_apply(const bf16* __restrict__ qkv, const float* __restrict__ rpe,
                const float* __restrict__ Mv, const float* __restrict__ xin,
                bf16* __restrict__ attout, int idx) {
    __shared__ __align__(16) bf16 lsP[4][64 * 64];
    __shared__ __align__(16) bf16 lsVt[4][32 * 64];
    const int bid = blockIdx.x;
    const int w = bid >> 2;
    const int tid = threadIdx.x, lane = tid & 63, wv = tid >> 6;
    const int h = (bid & 3) * 4 + wv;
    const int l15 = lane & 15, lg = lane >> 4;
    const long gbase = (idx == 0) ? (long)w * 64 : ((long)(w >> 6) * 4096 + (w & 63));
    const long gstride = (idx == 0) ? 1 : 64;
    const float Mw = Mv[w];
    bf16* P  = lsP[wv];
    bf16* Vt = lsVt[wv];

    {
        const int d4 = (lane & 7) * 4;
        #pragma unroll
        for (int it = 0; it < 8; ++it) {
            const int t = it * 8 + (lane >> 3);
            const bf16x4 v = *(const bf16x4*)
                &qkv[(gbase + (long)t * gstride) * 1536 + 1024 + h * 32 + d4];
            #pragma unroll
            for (int e = 0; e < 4; ++e) {
                const int d = d4 + e;
                Vt[d * 64 + (t ^ ((d & 7) * 8))] = v[e];
            }
        }
    }
    bf16x8 kf[4];
    #pragma unroll
    for (int i = 0; i < 4; ++i) {
        const long gs = gbase + (long)(i * 16 + l15) * gstride;
        kf[i] = *(const bf16x8*)&qkv[gs * 1536 + 512 + h * 32 + lg * 8];
    }
    const float* rh = rpe + h * 4096;
    #pragma unroll
    for (int mi = 0; mi < 4; ++mi) {
        const long gs = gbase + (long)(mi * 16 + l15) * gstride;
        const bf16x8 qf = *(const bf16x8*)&qkv[gs * 1536 + h * 32 + lg * 8];
        f32x4 sc[4] = {};
        #pragma unroll
        for (int ni = 0; ni < 4; ++ni) sc[ni] = mfma16(qf, kf[ni], sc[ni]);
        #pragma unroll
        for (int r = 0; r < 4; ++r) {
            const int srow = mi * 16 + lg * 4 + r;
            float vv[4], ssq = 0.f;
            #pragma unroll
            for (int ni = 0; ni < 4; ++ni) {
                const float v = sc[ni][r] + 0.1f * rh[srow * 64 + ni * 16 + l15];
                vv[ni] = v;
                ssq += v * v;
            }
            ssq += __shfl_xor(ssq, 1);
            ssq += __shfl_xor(ssq, 2);
            ssq += __shfl_xor(ssq, 4);
            ssq += __shfl_xor(ssq, 8);
            const float is = 1.0f / fmaxf(sqrtf(ssq), 1e-12f);
            #pragma unroll
            for (int ni = 0; ni < 4; ++ni) {
                const float v = (1.0f - __cosf(vv[ni] * is * 1.57079632679f)) * Mw;
                const int col = ni * 16 + l15;
                P[srow * 64 + (col ^ ((srow & 7) * 8))] = (bf16)v;
            }
        }
    }
    f32x4 acc[4][2] = {};
    #pragma unroll
    for (int kk = 0; kk < 2; ++kk) {
        bf16x8 bfr[2];
        #pragma unroll
        for (int dj = 0; dj < 2; ++dj) {
            const int d = dj * 16 + l15;
            bfr[dj] = *(const bf16x8*)&Vt[d * 64 + ((kk * 32 + lg * 8) ^ ((d & 7) * 8))];
        }
        #pragma unroll
        for (int mi = 0; mi < 4; ++mi) {
            const int s = mi * 16 + l15;
            const bf16x8 af = *(const bf16x8*)&P[s * 64 + ((kk * 32 + lg * 8) ^ ((s & 7) * 8))];
            #pragma unroll
            for (int dj = 0; dj < 2; ++dj)
                acc[mi][dj] = mfma16(af, bfr[dj], acc[mi][dj]);
        }
    }
    #pragma unroll
    for (int mi = 0; mi < 4; ++mi) {
        #pragma unroll
        for (int r = 0; r < 4; ++r) {
            const int s = mi * 16 + lg * 4 + r;
            const long gg = gbase + (long)s * gstride;
            const float rm = 1.0f - Mv[(int)(gg >> 6)];
            #pragma unroll
            for (int dj = 0; dj < 2; ++dj) {
                const int d = dj * 16 + l15;
                const size_t oidx = (size_t)gg * 512 + h * 32 + d;
                attout[oidx] = (bf16)(acc[mi][dj][r] + xin[oidx] * rm);
            }
        }
    }
}

// ---------------------------------------------------------------------------
// Host-side orchestration
// ---------------------------------------------------------------------------
extern "C" void kernel_launch(void* const* d_in, const int* in_sizes, int n_in,
                              void* d_out, int out_size, void* d_ws, size_t ws_size,
                              hipStream_t stream) {
    const float* x    = (const float*)d_in[0];
    const float* rpe0 = (const float*)d_in[1];
    const float* rpe1 = (const float*)d_in[2];
    auto W = [&](int i) { return (const float*)d_in[i]; };

    char* ws = (char*)d_ws;
    size_t off = 0;
    auto alloc = [&](size_t bytes) {
        void* p = ws + off;
        off += (bytes + 255) & ~(size_t)255;
        return p;
    };
    bf16 *wqkvT[2], *wprojT[2], *wfc1T[2], *wfc2T[2];
    for (int b = 0; b < 2; ++b) {
        wqkvT[b] = (bf16*)alloc((size_t)1536 * 512 * 2);
        wprojT[b] = (bf16*)alloc((size_t)512 * 512 * 2);
        wfc1T[b] = (bf16*)alloc((size_t)2048 * 512 * 2);
        wfc2T[b] = (bf16*)alloc((size_t)512 * 2048 * 2);
    }
    bf16* IMG = (bf16*)alloc((size_t)16384 * 512 * 2);
    bf16* QKV = (bf16*)alloc((size_t)16384 * 1536 * 2);
    bf16* ATT = (bf16*)alloc((size_t)16384 * 512 * 2);
    bf16* H1  = QKV;  // fc1 output [16384,2048] overlays QKV+ATT (both dead)
    float* X1    = (float*)alloc((size_t)16384 * 512 * 4);
    float* Mraw4 = (float*)alloc(1024 * 4);
    float* Mv    = (float*)alloc(256 * 4);
    float* XMID  = (float*)d_out;  // x after attention residual (fp32 spine)

    auto launchT = [&](const float* Wp, bf16* Wt, int K, int N) {
        transpose_cast<<<dim3(N / 32, K / 32), 256, 0, stream>>>(Wp, Wt, K, N);
    };
    launchT(W(5), wqkvT[0], 512, 1536);
    launchT(W(6), wprojT[0], 512, 512);
    launchT(W(10), wfc1T[0], 512, 2048);
    launchT(W(12), wfc2T[0], 2048, 512);
    launchT(W(16), wqkvT[1], 512, 1536);
    launchT(W(17), wprojT[1], 512, 512);
    launchT(W(21), wfc1T[1], 512, 2048);
    launchT(W(23), wfc2T[1], 2048, 512);

    for (int b = 0; b < 2; ++b) {
        const float* xin = (b == 0) ? x : X1;
        const float* rpe = (b == 0) ? rpe0 : rpe1;
        const int base = (b == 0) ? 3 : 14;
        const float* ln1g = W(base + 0);
        const float* ln1b = W(base + 1);
        const float* bproj = W(base + 4);
        const float* ln2g = W(base + 5);
        const float* ln2b = W(base + 6);
        const float* bfc1 = W(base + 8);
        const float* bfc2 = W(base + 10);

        // 1. LN1: xin -> IMG (bf16)
        ln_kernel<<<4096, 256, 0, stream>>>(xin, ln1g, ln1b, IMG);
        // 2. QKV GEMM (K=512): IMG @ wqkv -> QKV (bf16)
        gemm_bt<0, 512><<<dim3(12, 128), 512, 0, stream>>>(
            IMG, wqkvT[b], 1536, nullptr, nullptr, nullptr, QKV);
        // 3-4. gating scalar M per window
        attn_stats<<<1024, 256, 0, stream>>>(QKV, rpe, Mraw4, b);
        mcalc<<<1, 256, 0, stream>>>(Mraw4, Mv);
        // 5. attention apply -> ATT (bf16), includes masked residual
        attn_apply<<<1024, 256, 0, stream>>>(QKV, rpe, Mv, xin, ATT, b);
        // 6. proj GEMM (K=512): ATT @ wproj + bproj + xin -> XMID (fp32)
        gemm_bt<1, 512><<<dim3(4, 128), 512, 0, stream>>>(
            ATT, wprojT[b], 512, bproj, xin, XMID, nullptr);
        // 7. LN2: XMID -> IMG (bf16)
        ln_kernel<<<4096, 256, 0, stream>>>(XMID, ln2g, ln2b, IMG);
        // 8. FC1 + exact GELU (K=512): IMG @ wfc1 -> H1 (bf16)
        gemm_bt<2, 512><<<dim3(16, 128), 512, 0, stream>>>(
            IMG, wfc1T[b], 2048, bfc1, nullptr, nullptr, H1);
        // 9. FC2 (K=2048): H1 @ wfc2 + bfc2 + XMID -> (b==0 ? X1 : d_out)
        gemm_bt<1, 2048><<<dim3(4, 128), 512, 0, stream>>>(
            H1, wfc2T[b], 512, bfc2, XMID, (b == 0) ? X1 : XMID, nullptr);
    }
    (void)in_sizes; (void)n_in; (void)out_size; (void)ws_size;
}

// Round 12
// 475.329 us; speedup vs baseline: 1.0982x; 1.0982x over previous
//
#include <hip/hip_runtime.h>
#include <cstdint>
#include <cstddef>

typedef __bf16 bf16;
typedef __attribute__((ext_vector_type(4))) float f32x4;
typedef __attribute__((ext_vector_type(8))) __bf16 bf16x8;
typedef __attribute__((ext_vector_type(4))) __bf16 bf16x4;

static __device__ __forceinline__ f32x4 mfma16(bf16x8 a, bf16x8 b, f32x4 c) {
    return __builtin_amdgcn_mfma_f32_16x16x32_bf16(a, b, c, 0, 0, 0);
}

#define GLOAD_LDS16(gsrc, ldst)                                              \
    __builtin_amdgcn_global_load_lds(                                        \
        (const __attribute__((address_space(1))) void*)(gsrc),               \
        (__attribute__((address_space(3))) void*)(ldst), 16, 0, 0)

// ---------------------------------------------------------------------------
// Weight transpose + cast: Wt[n*K + k] = bf16(W[k*N + n])
// ---------------------------------------------------------------------------
__global__ __launch_bounds__(256)
void transpose_cast(const float* __restrict__ W, bf16* __restrict__ Wt, int K, int N) {
    __shared__ float tile[32][33];
    const int n0 = blockIdx.x * 32, k0 = blockIdx.y * 32;
    const int tx = threadIdx.x & 31, ty = threadIdx.x >> 5;  // ty 0..7
    #pragma unroll
    for (int i = ty; i < 32; i += 8)
        tile[i][tx] = W[(size_t)(k0 + i) * N + n0 + tx];
    __syncthreads();
    #pragma unroll
    for (int i = ty; i < 32; i += 8)
        Wt[(size_t)(n0 + i) * K + k0 + tx] = (bf16)tile[tx][i];
}

// ---------------------------------------------------------------------------
// LayerNorm over 512 cols, fp32 in -> bf16 out. 1 wave per row, 4 rows/block.
// ---------------------------------------------------------------------------
__global__ __launch_bounds__(256)
void ln_kernel(const float* __restrict__ x, const float* __restrict__ g,
               const float* __restrict__ b, bf16* __restrict__ out) {
    const int row = blockIdx.x * 4 + (threadIdx.x >> 6);
    const int lane = threadIdx.x & 63;
    const float* p = x + (size_t)row * 512 + lane * 8;
    const float4 a0 = *(const float4*)p;
    const float4 a1 = *(const float4*)(p + 4);
    float vx[8] = {a0.x, a0.y, a0.z, a0.w, a1.x, a1.y, a1.z, a1.w};
    float s = 0.f, ss = 0.f;
    #pragma unroll
    for (int k = 0; k < 8; ++k) { s += vx[k]; ss += vx[k] * vx[k]; }
    #pragma unroll
    for (int m = 1; m < 64; m <<= 1) {
        s  += __shfl_xor(s, m);
        ss += __shfl_xor(ss, m);
    }
    const float mean = s * (1.0f / 512.0f);
    const float var  = ss * (1.0f / 512.0f) - mean * mean;
    const float inv  = rsqrtf(var + 1e-5f);
    const int c0 = lane * 8;
    const float4 g0 = *(const float4*)&g[c0], g1 = *(const float4*)&g[c0 + 4];
    const float4 b0 = *(const float4*)&b[c0], b1 = *(const float4*)&b[c0 + 4];
    const float gv[8] = {g0.x, g0.y, g0.z, g0.w, g1.x, g1.y, g1.z, g1.w};
    const float bv[8] = {b0.x, b0.y, b0.z, b0.w, b1.x, b1.y, b1.z, b1.w};
    bf16x8 o;
    #pragma unroll
    for (int k = 0; k < 8; ++k)
        o[k] = (bf16)((vx[k] - mean) * inv * gv[k] + bv[k]);
    *(bf16x8*)&out[(size_t)row * 512 + c0] = o;
}

// ---------------------------------------------------------------------------
// GEMM: C[M,N] = A[M,K] bf16 x Bt[N,K]^T bf16. 128x128 tile, BK=32,
// 8 waves (512 thr), 2Mx4N wave grid -> per-wave 64x32 output (acc[4][2],
// 32 VGPR). __launch_bounds__(512,8): 32 waves/CU (verified occ ~74%).
// K template + #pragma unroll 16: K=512 (NK-1=15) fully unrolls (identical
// to R10's best FC1 codegen, address folding confirmed by VALUBusy drop);
// K=2048 unrolls in 16-step windows (R10's full 63-step unroll bloated FC2;
// R11's orientation flip was the regression -- reverted). Double-buffered
// 32KB linear LDS via global_load_lds(16B) + source slot swizzle, one
// barrier per K-step, XCD-chunked block swizzle. Epilogue via per-wave
// [16][36] LDS bounce, vectorized stores.
// EPI 0: bf16. EPI 1: +bias +res(fp32), fp32. EPI 2: +bias, GELU, bf16.
// ---------------------------------------------------------------------------
template <int EPI, int K>
__global__ __launch_bounds__(512, 8)
void gemm_bt(const bf16* __restrict__ A, const bf16* __restrict__ Bt,
             int N, const float* __restrict__ bias,
             const float* __restrict__ res, float* __restrict__ outf,
             bf16* __restrict__ outh) {
    __shared__ __align__(16) bf16 smem[16384];   // 32 KB
    auto lsA = [&](int buf) { return smem + buf * 4096; };
    auto lsB = [&](int buf) { return smem + 8192 + buf * 4096; };
    const int nx = gridDim.x;
    const int nwg = nx * gridDim.y;
    const int flat = blockIdx.y * nx + blockIdx.x;
    const int cpx = nwg >> 3;
    const int bswz = (flat & 7) * cpx + (flat >> 3);
    const int bn = bswz % nx, bm = bswz / nx;

    const int tid = threadIdx.x, lane = tid & 63, wv = tid >> 6;   // wv 0..7
    const int wr = wv >> 2, wc = wv & 3;        // 2M x 4N wave grid
    const int l15 = lane & 15, lg = lane >> 4;
    const size_t abase = (size_t)bm * 128 * K;
    const size_t bbase = (size_t)bn * 128 * K;
    // staging: wave wv stages 16-row chunk wv of A and of B (1 load each).
    const int sr = wv * 16 + (lane >> 2);        // global tile row
    const int ks = ((lane & 3) ^ ((sr >> 1) & 3)) * 8;  // swizzled k-offset
    const bf16* aSrc = &A[abase + (size_t)sr * K + ks];
    const bf16* bSrc = &Bt[bbase + (size_t)sr * K + ks];

    f32x4 acc[4][2] = {};

    auto stage = [&](int buf, int kt) {   // 2 loads/wave, kt folds to imm
        GLOAD_LDS16(aSrc + kt, lsA(buf) + wv * 512);
        GLOAD_LDS16(bSrc + kt, lsB(buf) + wv * 512);
    };
    auto compute = [&](int buf) {
        bf16x8 af[4], bfr[2];
        #pragma unroll
        for (int i = 0; i < 4; ++i) {
            const int r = wr * 64 + i * 16 + l15;
            af[i] = *(const bf16x8*)
                (lsA(buf) + r * 32 + ((lg ^ ((r >> 1) & 3)) * 8));
        }
        #pragma unroll
        for (int j = 0; j < 2; ++j) {
            const int r = wc * 32 + j * 16 + l15;
            bfr[j] = *(const bf16x8*)
                (lsB(buf) + r * 32 + ((lg ^ ((r >> 1) & 3)) * 8));
        }
        #pragma unroll
        for (int i = 0; i < 4; ++i)
            #pragma unroll
            for (int j = 0; j < 2; ++j)
                acc[i][j] = mfma16(af[i], bfr[j], acc[i][j]);
    };

    constexpr int NK = K >> 5;   // 16 (K=512) or 64 (K=2048)
    stage(0, 0);
    __syncthreads();
    #pragma unroll 16
    for (int t = 0; t < NK - 1; ++t) {
        stage((t + 1) & 1, (t + 1) * 32);
        compute(t & 1);
        __syncthreads();
    }
    compute((NK - 1) & 1);
    __syncthreads();   // staging LDS dead; reuse per-wave for epilogue pack

    // ---- vectorized epilogue via per-wave LDS bounce ----
    float* lsW = (float*)smem + wv * 1024;   // [16][36]
    const int orow = bm * 128 + wr * 64;
    const int ocol = bn * 128 + wc * 32;
    #pragma unroll
    for (int i = 0; i < 4; ++i) {
        #pragma unroll
        for (int r = 0; r < 4; ++r)
            #pragma unroll
            for (int j = 0; j < 2; ++j)
                lsW[(lg * 4 + r) * 36 + j * 16 + l15] = acc[i][j][r];
        __builtin_amdgcn_s_waitcnt(0);   // lgkmcnt(0): same-wave visibility
        if constexpr (EPI == 0 || EPI == 2) {
            const int rl = lane >> 2, c8 = (lane & 3) * 8;
            const float4 v0 = *(const float4*)&lsW[rl * 36 + c8];
            const float4 v1 = *(const float4*)&lsW[rl * 36 + c8 + 4];
            float vv[8] = {v0.x, v0.y, v0.z, v0.w, v1.x, v1.y, v1.z, v1.w};
            if constexpr (EPI == 2) {
                const float4 bb0 = *(const float4*)&bias[ocol + c8];
                const float4 bb1 = *(const float4*)&bias[ocol + c8 + 4];
                const float bv[8] = {bb0.x, bb0.y, bb0.z, bb0.w,
                                     bb1.x, bb1.y, bb1.z, bb1.w};
                #pragma unroll
                for (int e = 0; e < 8; ++e) {
                    const float t = vv[e] + bv[e];
                    vv[e] = 0.5f * t * (1.0f + erff(t * 0.70710678118f));
                }
            }
            bf16x8 o;
            #pragma unroll
            for (int e = 0; e < 8; ++e) o[e] = (bf16)vv[e];
            *(bf16x8*)&outh[(size_t)(orow + i * 16 + rl) * N + ocol + c8] = o;
        } else {
            const int c4 = (lane & 7) * 4;
            const float4 bb = *(const float4*)&bias[ocol + c4];
            #pragma unroll
            for (int ii = 0; ii < 2; ++ii) {
                const int rl = ii * 8 + (lane >> 3);
                const size_t gro = (size_t)(orow + i * 16 + rl) * N + ocol + c4;
                float4 v = *(const float4*)&lsW[rl * 36 + c4];
                const float4 rr = *(const float4*)&res[gro];
                v.x += bb.x + rr.x; v.y += bb.y + rr.y;
                v.z += bb.z + rr.z; v.w += bb.w + rr.w;
                *(float4*)&outf[gro] = v;
            }
        }
    }
}

// ---------------------------------------------------------------------------
// Attention stats: block = (window w = bid>>2, head quad q = bid&3), one head
// per wave. Partial |QK^T + 0.1*rpe| sums -> Mraw4[w*4+q] (deterministic).
// ---------------------------------------------------------------------------
__global__ __launch_bounds__(256)
void attn_stats(const bf16* __restrict__ qkv, const float* __restrict__ rpe,
                float* __restrict__ Mraw4, int idx) {
    __shared__ float lsum[4];
    const int bid = blockIdx.x;
    const int w = bid >> 2;
    const int tid = threadIdx.x, lane = tid & 63, wv = tid >> 6;
    const int h = (bid & 3) * 4 + wv;
    const int l15 = lane & 15, lg = lane >> 4;
    const long gbase = (idx == 0) ? (long)w * 64 : ((long)(w >> 6) * 4096 + (w & 63));
    const long gstride = (idx == 0) ? 1 : 64;
    bf16x8 kf[4];
    #pragma unroll
    for (int i = 0; i < 4; ++i) {
        const long gs = gbase + (long)(i * 16 + l15) * gstride;
        kf[i] = *(const bf16x8*)&qkv[gs * 1536 + 512 + h * 32 + lg * 8];
    }
    const float* rh = rpe + h * 4096;
    float asum = 0.f;
    #pragma unroll
    for (int mi = 0; mi < 4; ++mi) {
        const long gs = gbase + (long)(mi * 16 + l15) * gstride;
        const bf16x8 qf = *(const bf16x8*)&qkv[gs * 1536 + h * 32 + lg * 8];
        f32x4 sc[4] = {};
        #pragma unroll
        for (int ni = 0; ni < 4; ++ni) sc[ni] = mfma16(qf, kf[ni], sc[ni]);
        #pragma unroll
        for (int r = 0; r < 4; ++r) {
            const int srow = mi * 16 + lg * 4 + r;
            #pragma unroll
            for (int ni = 0; ni < 4; ++ni)
                asum += fabsf(sc[ni][r] + 0.1f * rh[srow * 64 + ni * 16 + l15]);
        }
    }
    #pragma unroll
    for (int m = 1; m < 64; m <<= 1) asum += __shfl_xor(asum, m);
    if (lane == 0) lsum[wv] = asum;
    __syncthreads();
    if (tid == 0) Mraw4[bid] = lsum[0] + lsum[1] + lsum[2] + lsum[3];
}

// M[w] = max( (sum(Mraw4[w*4..+3])/65536) / max_w(...), 0.5 )
__global__ __launch_bounds__(256)
void mcalc(const float* __restrict__ Mraw4, float* __restrict__ Mv) {
    __shared__ float red[4];
    const int t = threadIdx.x, lane = t & 63;
    const float v = (Mraw4[t * 4] + Mraw4[t * 4 + 1] + Mraw4[t * 4 + 2] +
                     Mraw4[t * 4 + 3]) * (1.0f / 65536.0f);
    float m = v;
    #pragma unroll
    for (int msk = 1; msk < 64; msk <<= 1) m = fmaxf(m, __shfl_xor(m, msk));
    if (lane == 0) red[t >> 6] = m;
    __syncthreads();
    const float mm = fmaxf(fmaxf(red[0], red[1]), fmaxf(red[2], red[3]));
    Mv[t] = fmaxf(v / mm, 0.5f);
}

// ---------------------------------------------------------------------------
// Attention apply: block = (window, head quad), one head per wave.
// QK^T (MFMA) -> +0.1*rpe -> row L2-norm -> 1-cos -> *M -> P in swizzled LDS
// -> PV via MFMA with V^T in swizzled LDS -> unpartition + masked residual.
// ---------------------------------------------------------------------------
__global__ __launch_bounds__(256)
void attn_apply(const bf16* __restrict__ qkv, const float* __restrict__ rpe,
                const float* __restrict__ Mv, const float* __restrict__ xin,
                bf16* __restrict__ attout, int idx) {
    __shared__ __align__(16) bf16 lsP[4][64 * 64];
    __shared__ __align__(16) bf16 lsVt[4][32 * 64];
    const int bid = blockIdx.x;
    const int w = bid >> 2;
    const int tid = threadIdx.x, lane = tid & 63, wv = tid >> 6;
    const int h = (bid & 3) * 4 + wv;
    const int l15 = lane & 15, lg = lane >> 4;
    const long gbase = (idx == 0) ? (long)w * 64 : ((long)(w >> 6) * 4096 + (w & 63));
    const long gstride = (idx == 0) ? 1 : 64;
    const float Mw = Mv[w];
    bf16* P  = lsP[wv];
    bf16* Vt = lsVt[wv];

    {
        const int d4 = (lane & 7) * 4;
        #pragma unroll
        for (int it = 0; it < 8; ++it) {
            const int t = it * 8 + (lane >> 3);
            const bf16x4 v = *(const bf16x4*)
                &qkv[(gbase + (long)t * gstride) * 1536 + 1024 + h * 32 + d4];
            #pragma unroll
            for (int e = 0; e < 4; ++e) {
                const int d = d4 + e;
                Vt[d * 64 + (t ^ ((d & 7) * 8))] = v[e];
            }
        }
    }
    bf16x8 kf[4];
    #pragma unroll
    for (int i = 0; i < 4; ++i) {
        const long gs = gbase + (long)(i * 16 + l15) * gstride;
        kf[i] = *(const bf16x8*)&qkv[gs * 1536 + 512 + h * 32 + lg * 8];
    }
    const float* rh = rpe + h * 4096;
    #pragma unroll
    for (int mi = 0; mi < 4; ++mi) {
        const long gs = gbase + (long)(mi * 16 + l15) * gstride;
        const bf16x8 qf = *(const bf16x8*)&qkv[gs * 1536 + h * 32 + lg * 8];
        f32x4 sc[4] = {};
        #pragma unroll
        for (int ni = 0; ni < 4; ++ni) sc[ni] = mfma16(qf, kf[ni], sc[ni]);
        #pragma unroll
        for (int r = 0; r < 4; ++r) {
            const int srow = mi * 16 + lg * 4 + r;
            float vv[4], ssq = 0.f;
            #pragma unroll
            for (int ni = 0; ni < 4; ++ni) {
                const float v = sc[ni][r] + 0.1f * rh[srow * 64 + ni * 16 + l15];
                vv[ni] = v;
                ssq += v * v;
            }
            ssq += __shfl_xor(ssq, 1);
            ssq += __shfl_xor(ssq, 2);
            ssq += __shfl_xor(ssq, 4);
            ssq += __shfl_xor(ssq, 8);
            const float is = 1.0f / fmaxf(sqrtf(ssq), 1e-12f);
            #pragma unroll
            for (int ni = 0; ni < 4; ++ni) {
                const float v = (1.0f - __cosf(vv[ni] * is * 1.57079632679f)) * Mw;
                const int col = ni * 16 + l15;
                P[srow * 64 + (col ^ ((srow & 7) * 8))] = (bf16)v;
            }
        }
    }
    f32x4 acc[4][2] = {};
    #pragma unroll
    for (int kk = 0; kk < 2; ++kk) {
        bf16x8 bfr[2];
        #pragma unroll
        for (int dj = 0; dj < 2; ++dj) {
            const int d = dj * 16 + l15;
            bfr[dj] = *(const bf16x8*)&Vt[d * 64 + ((kk * 32 + lg * 8) ^ ((d & 7) * 8))];
        }
        #pragma unroll
        for (int mi = 0; mi < 4; ++mi) {
            const int s = mi * 16 + l15;
            const bf16x8 af = *(const bf16x8*)&P[s * 64 + ((kk * 32 + lg * 8) ^ ((s & 7) * 8))];
            #pragma unroll
            for (int dj = 0; dj < 2; ++dj)
                acc[mi][dj] = mfma16(af, bfr[dj], acc[mi][dj]);
        }
    }
    #pragma unroll
    for (int mi = 0; mi < 4; ++mi) {
        #pragma unroll
        for (int r = 0; r < 4; ++r) {
            const int s = mi * 16 + lg * 4 + r;
            const long gg = gbase + (long)s * gstride;
            const float rm = 1.0f - Mv[(int)(gg >> 6)];
            #pragma unroll
            for (int dj = 0; dj < 2; ++dj) {
                const int d = dj * 16 + l15;
                const size_t oidx = (size_t)gg * 512 + h * 32 + d;
                attout[oidx] = (bf16)(acc[mi][dj][r] + xin[oidx] * rm);
            }
        }
    }
}

// ---------------------------------------------------------------------------
// Host-side orchestration
// ---------------------------------------------------------------------------
extern "C" void kernel_launch(void* const* d_in, const int* in_sizes, int n_in,
                              void* d_out, int out_size, void* d_ws, size_t ws_size,
                              hipStream_t stream) {
    const float* x    = (const float*)d_in[0];
    const float* rpe0 = (const float*)d_in[1];
    const float* rpe1 = (const float*)d_in[2];
    auto W = [&](int i) { return (const float*)d_in[i]; };

    char* ws = (char*)d_ws;
    size_t off = 0;
    auto alloc = [&](size_t bytes) {
        void* p = ws + off;
        off += (bytes + 255) & ~(size_t)255;
        return p;
    };
    bf16 *wqkvT[2], *wprojT[2], *wfc1T[2], *wfc2T[2];
    for (int b = 0; b < 2; ++b) {
        wqkvT[b] = (bf16*)alloc((size_t)1536 * 512 * 2);
        wprojT[b] = (bf16*)alloc((size_t)512 * 512 * 2);
        wfc1T[b] = (bf16*)alloc((size_t)2048 * 512 * 2);
        wfc2T[b] = (bf16*)alloc((size_t)512 * 2048 * 2);
    }
    bf16* IMG = (bf16*)alloc((size_t)16384 * 512 * 2);
    bf16* QKV = (bf16*)alloc((size_t)16384 * 1536 * 2);
    bf16* ATT = (bf16*)alloc((size_t)16384 * 512 * 2);
    bf16* H1  = QKV;  // fc1 output [16384,2048] overlays QKV+ATT (both dead)
    float* X1    = (float*)alloc((size_t)16384 * 512 * 4);
    float* Mraw4 = (float*)alloc(1024 * 4);
    float* Mv    = (float*)alloc(256 * 4);
    float* XMID  = (float*)d_out;  // x after attention residual (fp32 spine)

    auto launchT = [&](const float* Wp, bf16* Wt, int K, int N) {
        transpose_cast<<<dim3(N / 32, K / 32), 256, 0, stream>>>(Wp, Wt, K, N);
    };
    launchT(W(5), wqkvT[0], 512, 1536);
    launchT(W(6), wprojT[0], 512, 512);
    launchT(W(10), wfc1T[0], 512, 2048);
    launchT(W(12), wfc2T[0], 2048, 512);
    launchT(W(16), wqkvT[1], 512, 1536);
    launchT(W(17), wprojT[1], 512, 512);
    launchT(W(21), wfc1T[1], 512, 2048);
    launchT(W(23), wfc2T[1], 2048, 512);

    for (int b = 0; b < 2; ++b) {
        const float* xin = (b == 0) ? x : X1;
        const float* rpe = (b == 0) ? rpe0 : rpe1;
        const int base = (b == 0) ? 3 : 14;
        const float* ln1g = W(base + 0);
        const float* ln1b = W(base + 1);
        const float* bproj = W(base + 4);
        const float* ln2g = W(base + 5);
        const float* ln2b = W(base + 6);
        const float* bfc1 = W(base + 8);
        const float* bfc2 = W(base + 10);

        // 1. LN1: xin -> IMG (bf16)
        ln_kernel<<<4096, 256, 0, stream>>>(xin, ln1g, ln1b, IMG);
        // 2. QKV GEMM (K=512): IMG @ wqkv -> QKV (bf16)
        gemm_bt<0, 512><<<dim3(12, 128), 512, 0, stream>>>(
            IMG, wqkvT[b], 1536, nullptr, nullptr, nullptr, QKV);
        // 3-4. gating scalar M per window
        attn_stats<<<1024, 256, 0, stream>>>(QKV, rpe, Mraw4, b);
        mcalc<<<1, 256, 0, stream>>>(Mraw4, Mv);
        // 5. attention apply -> ATT (bf16), includes masked residual
        attn_apply<<<1024, 256, 0, stream>>>(QKV, rpe, Mv, xin, ATT, b);
        // 6. proj GEMM (K=512): ATT @ wproj + bproj + xin -> XMID (fp32)
        gemm_bt<1, 512><<<dim3(4, 128), 512, 0, stream>>>(
            ATT, wprojT[b], 512, bproj, xin, XMID, nullptr);
        // 7. LN2: XMID -> IMG (bf16)
        ln_kernel<<<4096, 256, 0, stream>>>(XMID, ln2g, ln2b, IMG);
        // 8. FC1 + exact GELU (K=512): IMG @ wfc1 -> H1 (bf16)
        gemm_bt<2, 512><<<dim3(16, 128), 512, 0, stream>>>(
            IMG, wfc1T[b], 2048, bfc1, nullptr, nullptr, H1);
        // 9. FC2 (K=2048): H1 @ wfc2 + bfc2 + XMID -> (b==0 ? X1 : d_out)
        gemm_bt<1, 2048><<<dim3(4, 128), 512, 0, stream>>>(
            H1, wfc2T[b], 512, bfc2, XMID, (b == 0) ? X1 : XMID, nullptr);
    }
    (void)in_sizes; (void)n_in; (void)out_size; (void)ws_size;
}

// Round 13
// 451.134 us; speedup vs baseline: 1.1571x; 1.0536x over previous
//
#include <hip/hip_runtime.h>
#include <cstdint>
#include <cstddef>

typedef __bf16 bf16;
typedef __attribute__((ext_vector_type(4))) float f32x4;
typedef __attribute__((ext_vector_type(8))) __bf16 bf16x8;
typedef __attribute__((ext_vector_type(4))) __bf16 bf16x4;

static __device__ __forceinline__ f32x4 mfma16(bf16x8 a, bf16x8 b, f32x4 c) {
    return __builtin_amdgcn_mfma_f32_16x16x32_bf16(a, b, c, 0, 0, 0);
}

#define GLOAD_LDS16(gsrc, ldst)                                              \
    __builtin_amdgcn_global_load_lds(                                        \
        (const __attribute__((address_space(1))) void*)(gsrc),               \
        (__attribute__((address_space(3))) void*)(ldst), 16, 0, 0)

// ---------------------------------------------------------------------------
// Weight transpose + cast: Wt[n*K + k] = bf16(W[k*N + n])
// ---------------------------------------------------------------------------
__global__ __launch_bounds__(256)
void transpose_cast(const float* __restrict__ W, bf16* __restrict__ Wt, int K, int N) {
    __shared__ float tile[32][33];
    const int n0 = blockIdx.x * 32, k0 = blockIdx.y * 32;
    const int tx = threadIdx.x & 31, ty = threadIdx.x >> 5;  // ty 0..7
    #pragma unroll
    for (int i = ty; i < 32; i += 8)
        tile[i][tx] = W[(size_t)(k0 + i) * N + n0 + tx];
    __syncthreads();
    #pragma unroll
    for (int i = ty; i < 32; i += 8)
        Wt[(size_t)(n0 + i) * K + k0 + tx] = (bf16)tile[tx][i];
}

// ---------------------------------------------------------------------------
// LayerNorm over 512 cols, fp32 in -> bf16 out. 1 wave per row, 4 rows/block.
// ---------------------------------------------------------------------------
__global__ __launch_bounds__(256)
void ln_kernel(const float* __restrict__ x, const float* __restrict__ g,
               const float* __restrict__ b, bf16* __restrict__ out) {
    const int row = blockIdx.x * 4 + (threadIdx.x >> 6);
    const int lane = threadIdx.x & 63;
    const float* p = x + (size_t)row * 512 + lane * 8;
    const float4 a0 = *(const float4*)p;
    const float4 a1 = *(const float4*)(p + 4);
    float vx[8] = {a0.x, a0.y, a0.z, a0.w, a1.x, a1.y, a1.z, a1.w};
    float s = 0.f, ss = 0.f;
    #pragma unroll
    for (int k = 0; k < 8; ++k) { s += vx[k]; ss += vx[k] * vx[k]; }
    #pragma unroll
    for (int m = 1; m < 64; m <<= 1) {
        s  += __shfl_xor(s, m);
        ss += __shfl_xor(ss, m);
    }
    const float mean = s * (1.0f / 512.0f);
    const float var  = ss * (1.0f / 512.0f) - mean * mean;
    const float inv  = rsqrtf(var + 1e-5f);
    const int c0 = lane * 8;
    const float4 g0 = *(const float4*)&g[c0], g1 = *(const float4*)&g[c0 + 4];
    const float4 b0 = *(const float4*)&b[c0], b1 = *(const float4*)&b[c0 + 4];
    const float gv[8] = {g0.x, g0.y, g0.z, g0.w, g1.x, g1.y, g1.z, g1.w};
    const float bv[8] = {b0.x, b0.y, b0.z, b0.w, b1.x, b1.y, b1.z, b1.w};
    bf16x8 o;
    #pragma unroll
    for (int k = 0; k < 8; ++k)
        o[k] = (bf16)((vx[k] - mean) * inv * gv[k] + bv[k]);
    *(bf16x8*)&out[(size_t)row * 512 + c0] = o;
}

// ---------------------------------------------------------------------------
// GEMM: C[M,N] = A[M,K] bf16 x Bt[N,K]^T bf16. 128x128 tile, BK=32,
// 8 waves (512 thr), 2Mx4N wave grid -> per-wave 64x32 output (acc[4][2],
// 32 VGPR). __launch_bounds__(512,8): 32 waves/CU (occ ~74% verified).
// HYBRID K policy (R9-R12 ledger): KT>0 -> fully-unrolled static-K loop
// (best for K=512: FC1 78->70us, address folding confirmed); KT==0 ->
// R9's compact runtime-K loop (best for K=2048: static unrolling of NK=64
// regressed FC2 in both R10 and R12). Double-buffered 32KB linear LDS via
// global_load_lds(16B) + source slot swizzle, one barrier per K-step,
// XCD-chunked block swizzle. Epilogue via per-wave [16][36] LDS bounce.
// EPI 0: bf16. EPI 1: +bias +res(fp32), fp32. EPI 2: +bias, GELU, bf16.
// ---------------------------------------------------------------------------
template <int EPI, int KT>
__global__ __launch_bounds__(512, 8)
void gemm_bt(const bf16* __restrict__ A, const bf16* __restrict__ Bt,
             int N, int Krt, const float* __restrict__ bias,
             const float* __restrict__ res, float* __restrict__ outf,
             bf16* __restrict__ outh) {
    const int K = (KT > 0) ? KT : Krt;
    __shared__ __align__(16) bf16 smem[16384];   // 32 KB
    auto lsA = [&](int buf) { return smem + buf * 4096; };
    auto lsB = [&](int buf) { return smem + 8192 + buf * 4096; };
    const int nx = gridDim.x;
    const int nwg = nx * gridDim.y;
    const int flat = blockIdx.y * nx + blockIdx.x;
    const int cpx = nwg >> 3;
    const int bswz = (flat & 7) * cpx + (flat >> 3);
    const int bn = bswz % nx, bm = bswz / nx;

    const int tid = threadIdx.x, lane = tid & 63, wv = tid >> 6;   // wv 0..7
    const int wr = wv >> 2, wc = wv & 3;        // 2M x 4N wave grid
    const int l15 = lane & 15, lg = lane >> 4;
    const size_t abase = (size_t)bm * 128 * K;
    const size_t bbase = (size_t)bn * 128 * K;
    // staging: wave wv stages 16-row chunk wv of A and of B (1 load each).
    const int sr = wv * 16 + (lane >> 2);        // global tile row
    const int ks = ((lane & 3) ^ ((sr >> 1) & 3)) * 8;  // swizzled k-offset
    const bf16* aSrc = &A[abase + (size_t)sr * K + ks];
    const bf16* bSrc = &Bt[bbase + (size_t)sr * K + ks];

    f32x4 acc[4][2] = {};

    auto stage = [&](int buf, int kt) {   // 2 loads/wave
        GLOAD_LDS16(aSrc + kt, lsA(buf) + wv * 512);
        GLOAD_LDS16(bSrc + kt, lsB(buf) + wv * 512);
    };
    auto compute = [&](int buf) {
        bf16x8 af[4], bfr[2];
        #pragma unroll
        for (int i = 0; i < 4; ++i) {
            const int r = wr * 64 + i * 16 + l15;
            af[i] = *(const bf16x8*)
                (lsA(buf) + r * 32 + ((lg ^ ((r >> 1) & 3)) * 8));
        }
        #pragma unroll
        for (int j = 0; j < 2; ++j) {
            const int r = wc * 32 + j * 16 + l15;
            bfr[j] = *(const bf16x8*)
                (lsB(buf) + r * 32 + ((lg ^ ((r >> 1) & 3)) * 8));
        }
        #pragma unroll
        for (int i = 0; i < 4; ++i)
            #pragma unroll
            for (int j = 0; j < 2; ++j)
                acc[i][j] = mfma16(af[i], bfr[j], acc[i][j]);
    };

    if constexpr (KT > 0) {
        constexpr int NK = KT >> 5;        // 16 for K=512
        stage(0, 0);
        __syncthreads();
        #pragma unroll
        for (int t = 0; t < NK - 1; ++t) {
            stage((t + 1) & 1, (t + 1) * 32);   // consts fold to immediates
            compute(t & 1);
            __syncthreads();
        }
        compute((NK - 1) & 1);
        __syncthreads();
    } else {
        const int NK = K >> 5;             // runtime loop (R9 codegen)
        stage(0, 0);
        __syncthreads();
        int cur = 0;
        for (int t = 0; t < NK - 1; ++t) {
            stage(cur ^ 1, (t + 1) * 32);
            compute(cur);
            __syncthreads();
            cur ^= 1;
        }
        compute(cur);
        __syncthreads();
    }

    // ---- vectorized epilogue via per-wave LDS bounce ----
    float* lsW = (float*)smem + wv * 1024;   // [16][36]
    const int orow = bm * 128 + wr * 64;
    const int ocol = bn * 128 + wc * 32;
    #pragma unroll
    for (int i = 0; i < 4; ++i) {
        #pragma unroll
        for (int r = 0; r < 4; ++r)
            #pragma unroll
            for (int j = 0; j < 2; ++j)
                lsW[(lg * 4 + r) * 36 + j * 16 + l15] = acc[i][j][r];
        __builtin_amdgcn_s_waitcnt(0);   // lgkmcnt(0): same-wave visibility
        if constexpr (EPI == 0 || EPI == 2) {
            const int rl = lane >> 2, c8 = (lane & 3) * 8;
            const float4 v0 = *(const float4*)&lsW[rl * 36 + c8];
            const float4 v1 = *(const float4*)&lsW[rl * 36 + c8 + 4];
            float vv[8] = {v0.x, v0.y, v0.z, v0.w, v1.x, v1.y, v1.z, v1.w};
            if constexpr (EPI == 2) {
                const float4 bb0 = *(const float4*)&bias[ocol + c8];
                const float4 bb1 = *(const float4*)&bias[ocol + c8 + 4];
                const float bv[8] = {bb0.x, bb0.y, bb0.z, bb0.w,
                                     bb1.x, bb1.y, bb1.z, bb1.w};
                #pragma unroll
                for (int e = 0; e < 8; ++e) {
                    const float t = vv[e] + bv[e];
                    vv[e] = 0.5f * t * (1.0f + erff(t * 0.70710678118f));
                }
            }
            bf16x8 o;
            #pragma unroll
            for (int e = 0; e < 8; ++e) o[e] = (bf16)vv[e];
            *(bf16x8*)&outh[(size_t)(orow + i * 16 + rl) * N + ocol + c8] = o;
        } else {
            const int c4 = (lane & 7) * 4;
            const float4 bb = *(const float4*)&bias[ocol + c4];
            #pragma unroll
            for (int ii = 0; ii < 2; ++ii) {
                const int rl = ii * 8 + (lane >> 3);
                const size_t gro = (size_t)(orow + i * 16 + rl) * N + ocol + c4;
                float4 v = *(const float4*)&lsW[rl * 36 + c4];
                const float4 rr = *(const float4*)&res[gro];
                v.x += bb.x + rr.x; v.y += bb.y + rr.y;
                v.z += bb.z + rr.z; v.w += bb.w + rr.w;
                *(float4*)&outf[gro] = v;
            }
        }
    }
}

// ---------------------------------------------------------------------------
// Attention stats: block = (window w = bid>>2, head quad q = bid&3), one head
// per wave. Partial |QK^T + 0.1*rpe| sums -> Mraw4[w*4+q] (deterministic).
// ---------------------------------------------------------------------------
__global__ __launch_bounds__(256)
void attn_stats(const bf16* __restrict__ qkv, const float* __restrict__ rpe,
                float* __restrict__ Mraw4, int idx) {
    __shared__ float lsum[4];
    const int bid = blockIdx.x;
    const int w = bid >> 2;
    const int tid = threadIdx.x, lane = tid & 63, wv = tid >> 6;
    const int h = (bid & 3) * 4 + wv;
    const int l15 = lane & 15, lg = lane >> 4;
    const long gbase = (idx == 0) ? (long)w * 64 : ((long)(w >> 6) * 4096 + (w & 63));
    const long gstride = (idx == 0) ? 1 : 64;
    bf16x8 kf[4];
    #pragma unroll
    for (int i = 0; i < 4; ++i) {
        const long gs = gbase + (long)(i * 16 + l15) * gstride;
        kf[i] = *(const bf16x8*)&qkv[gs * 1536 + 512 + h * 32 + lg * 8];
    }
    const float* rh = rpe + h * 4096;
    float asum = 0.f;
    #pragma unroll
    for (int mi = 0; mi < 4; ++mi) {
        const long gs = gbase + (long)(mi * 16 + l15) * gstride;
        const bf16x8 qf = *(const bf16x8*)&qkv[gs * 1536 + h * 32 + lg * 8];
        f32x4 sc[4] = {};
        #pragma unroll
        for (int ni = 0; ni < 4; ++ni) sc[ni] = mfma16(qf, kf[ni], sc[ni]);
        #pragma unroll
        for (int r = 0; r < 4; ++r) {
            const int srow = mi * 16 + lg * 4 + r;
            #pragma unroll
            for (int ni = 0; ni < 4; ++ni)
                asum += fabsf(sc[ni][r] + 0.1f * rh[srow * 64 + ni * 16 + l15]);
        }
    }
    #pragma unroll
    for (int m = 1; m < 64; m <<= 1) asum += __shfl_xor(asum, m);
    if (lane == 0) lsum[wv] = asum;
    __syncthreads();
    if (tid == 0) Mraw4[bid] = lsum[0] + lsum[1] + lsum[2] + lsum[3];
}

// M[w] = max( (sum(Mraw4[w*4..+3])/65536) / max_w(...), 0.5 )
__global__ __launch_bounds__(256)
void mcalc(const float* __restrict__ Mraw4, float* __restrict__ Mv) {
    __shared__ float red[4];
    const int t = threadIdx.x, lane = t & 63;
    const float v = (Mraw4[t * 4] + Mraw4[t * 4 + 1] + Mraw4[t * 4 + 2] +
                     Mraw4[t * 4 + 3]) * (1.0f / 65536.0f);
    float m = v;
    #pragma unroll
    for (int msk = 1; msk < 64; msk <<= 1) m = fmaxf(m, __shfl_xor(m, msk));
    if (lane == 0) red[t >> 6] = m;
    __syncthreads();
    const float mm = fmaxf(fmaxf(red[0], red[1]), fmaxf(red[2], red[3]));
    Mv[t] = fmaxf(v / mm, 0.5f);
}

// ---------------------------------------------------------------------------
// Attention apply: block = (window, head quad), one head per wave.
// QK^T (MFMA) -> +0.1*rpe -> row L2-norm -> 1-cos -> *M -> P in swizzled LDS
// -> PV via MFMA with V^T in swizzled LDS -> unpartition + masked residual.
// ---------------------------------------------------------------------------
__global__ __launch_bounds__(256)
void attn_apply(const bf16* __restrict__ qkv, const float* __restrict__ rpe,
                const float* __restrict__ Mv, const float* __restrict__ xin,
                bf16* __restrict__ attout, int idx) {
    __shared__ __align__(16) bf16 lsP[4][64 * 64];
    __shared__ __align__(16) bf16 lsVt[4][32 * 64];
    const int bid = blockIdx.x;
    const int w = bid >> 2;
    const int tid = threadIdx.x, lane = tid & 63, wv = tid >> 6;
    const int h = (bid & 3) * 4 + wv;
    const int l15 = lane & 15, lg = lane >> 4;
    const long gbase = (idx == 0) ? (long)w * 64 : ((long)(w >> 6) * 4096 + (w & 63));
    const long gstride = (idx == 0) ? 1 : 64;
    const float Mw = Mv[w];
    bf16* P  = lsP[wv];
    bf16* Vt = lsVt[wv];

    {
        const int d4 = (lane & 7) * 4;
        #pragma unroll
        for (int it = 0; it < 8; ++it) {
            const int t = it * 8 + (lane >> 3);
            const bf16x4 v = *(const bf16x4*)
                &qkv[(gbase + (long)t * gstride) * 1536 + 1024 + h * 32 + d4];
            #pragma unroll
            for (int e = 0; e < 4; ++e) {
                const int d = d4 + e;
                Vt[d * 64 + (t ^ ((d & 7) * 8))] = v[e];
            }
        }
    }
    bf16x8 kf[4];
    #pragma unroll
    for (int i = 0; i < 4; ++i) {
        const long gs = gbase + (long)(i * 16 + l15) * gstride;
        kf[i] = *(const bf16x8*)&qkv[gs * 1536 + 512 + h * 32 + lg * 8];
    }
    const float* rh = rpe + h * 4096;
    #pragma unroll
    for (int mi = 0; mi < 4; ++mi) {
        const long gs = gbase + (long)(mi * 16 + l15) * gstride;
        const bf16x8 qf = *(const bf16x8*)&qkv[gs * 1536 + h * 32 + lg * 8];
        f32x4 sc[4] = {};
        #pragma unroll
        for (int ni = 0; ni < 4; ++ni) sc[ni] = mfma16(qf, kf[ni], sc[ni]);
        #pragma unroll
        for (int r = 0; r < 4; ++r) {
            const int srow = mi * 16 + lg * 4 + r;
            float vv[4], ssq = 0.f;
            #pragma unroll
            for (int ni = 0; ni < 4; ++ni) {
                const float v = sc[ni][r] + 0.1f * rh[srow * 64 + ni * 16 + l15];
                vv[ni] = v;
                ssq += v * v;
            }
            ssq += __shfl_xor(ssq, 1);
            ssq += __shfl_xor(ssq, 2);
            ssq += __shfl_xor(ssq, 4);
            ssq += __shfl_xor(ssq, 8);
            const float is = 1.0f / fmaxf(sqrtf(ssq), 1e-12f);
            #pragma unroll
            for (int ni = 0; ni < 4; ++ni) {
                const float v = (1.0f - __cosf(vv[ni] * is * 1.57079632679f)) * Mw;
                const int col = ni * 16 + l15;
                P[srow * 64 + (col ^ ((srow & 7) * 8))] = (bf16)v;
            }
        }
    }
    f32x4 acc[4][2] = {};
    #pragma unroll
    for (int kk = 0; kk < 2; ++kk) {
        bf16x8 bfr[2];
        #pragma unroll
        for (int dj = 0; dj < 2; ++dj) {
            const int d = dj * 16 + l15;
            bfr[dj] = *(const bf16x8*)&Vt[d * 64 + ((kk * 32 + lg * 8) ^ ((d & 7) * 8))];
        }
        #pragma unroll
        for (int mi = 0; mi < 4; ++mi) {
            const int s = mi * 16 + l15;
            const bf16x8 af = *(const bf16x8*)&P[s * 64 + ((kk * 32 + lg * 8) ^ ((s & 7) * 8))];
            #pragma unroll
            for (int dj = 0; dj < 2; ++dj)
                acc[mi][dj] = mfma16(af, bfr[dj], acc[mi][dj]);
        }
    }
    #pragma unroll
    for (int mi = 0; mi < 4; ++mi) {
        #pragma unroll
        for (int r = 0; r < 4; ++r) {
            const int s = mi * 16 + lg * 4 + r;
            const long gg = gbase + (long)s * gstride;
            const float rm = 1.0f - Mv[(int)(gg >> 6)];
            #pragma unroll
            for (int dj = 0; dj < 2; ++dj) {
                const int d = dj * 16 + l15;
                const size_t oidx = (size_t)gg * 512 + h * 32 + d;
                attout[oidx] = (bf16)(acc[mi][dj][r] + xin[oidx] * rm);
            }
        }
    }
}

// ---------------------------------------------------------------------------
// Host-side orchestration
// ---------------------------------------------------------------------------
extern "C" void kernel_launch(void* const* d_in, const int* in_sizes, int n_in,
                              void* d_out, int out_size, void* d_ws, size_t ws_size,
                              hipStream_t stream) {
    const float* x    = (const float*)d_in[0];
    const float* rpe0 = (const float*)d_in[1];
    const float* rpe1 = (const float*)d_in[2];
    auto W = [&](int i) { return (const float*)d_in[i]; };

    char* ws = (char*)d_ws;
    size_t off = 0;
    auto alloc = [&](size_t bytes) {
        void* p = ws + off;
        off += (bytes + 255) & ~(size_t)255;
        return p;
    };
    bf16 *wqkvT[2], *wprojT[2], *wfc1T[2], *wfc2T[2];
    for (int b = 0; b < 2; ++b) {
        wqkvT[b] = (bf16*)alloc((size_t)1536 * 512 * 2);
        wprojT[b] = (bf16*)alloc((size_t)512 * 512 * 2);
        wfc1T[b] = (bf16*)alloc((size_t)2048 * 512 * 2);
        wfc2T[b] = (bf16*)alloc((size_t)512 * 2048 * 2);
    }
    bf16* IMG = (bf16*)alloc((size_t)16384 * 512 * 2);
    bf16* QKV = (bf16*)alloc((size_t)16384 * 1536 * 2);
    bf16* ATT = (bf16*)alloc((size_t)16384 * 512 * 2);
    bf16* H1  = QKV;  // fc1 output [16384,2048] overlays QKV+ATT (both dead)
    float* X1    = (float*)alloc((size_t)16384 * 512 * 4);
    float* Mraw4 = (float*)alloc(1024 * 4);
    float* Mv    = (float*)alloc(256 * 4);
    float* XMID  = (float*)d_out;  // x after attention residual (fp32 spine)

    auto launchT = [&](const float* Wp, bf16* Wt, int K, int N) {
        transpose_cast<<<dim3(N / 32, K / 32), 256, 0, stream>>>(Wp, Wt, K, N);
    };
    launchT(W(5), wqkvT[0], 512, 1536);
    launchT(W(6), wprojT[0], 512, 512);
    launchT(W(10), wfc1T[0], 512, 2048);
    launchT(W(12), wfc2T[0], 2048, 512);
    launchT(W(16), wqkvT[1], 512, 1536);
    launchT(W(17), wprojT[1], 512, 512);
    launchT(W(21), wfc1T[1], 512, 2048);
    launchT(W(23), wfc2T[1], 2048, 512);

    for (int b = 0; b < 2; ++b) {
        const float* xin = (b == 0) ? x : X1;
        const float* rpe = (b == 0) ? rpe0 : rpe1;
        const int base = (b == 0) ? 3 : 14;
        const float* ln1g = W(base + 0);
        const float* ln1b = W(base + 1);
        const float* bproj = W(base + 4);
        const float* ln2g = W(base + 5);
        const float* ln2b = W(base + 6);
        const float* bfc1 = W(base + 8);
        const float* bfc2 = W(base + 10);

        // 1. LN1: xin -> IMG (bf16)
        ln_kernel<<<4096, 256, 0, stream>>>(xin, ln1g, ln1b, IMG);
        // 2. QKV GEMM (K=512 static): IMG @ wqkv -> QKV (bf16)
        gemm_bt<0, 512><<<dim3(12, 128), 512, 0, stream>>>(
            IMG, wqkvT[b], 1536, 512, nullptr, nullptr, nullptr, QKV);
        // 3-4. gating scalar M per window
        attn_stats<<<1024, 256, 0, stream>>>(QKV, rpe, Mraw4, b);
        mcalc<<<1, 256, 0, stream>>>(Mraw4, Mv);
        // 5. attention apply -> ATT (bf16), includes masked residual
        attn_apply<<<1024, 256, 0, stream>>>(QKV, rpe, Mv, xin, ATT, b);
        // 6. proj GEMM (K=512 static): ATT @ wproj + bproj + xin -> XMID
        gemm_bt<1, 512><<<dim3(4, 128), 512, 0, stream>>>(
            ATT, wprojT[b], 512, 512, bproj, xin, XMID, nullptr);
        // 7. LN2: XMID -> IMG (bf16)
        ln_kernel<<<4096, 256, 0, stream>>>(XMID, ln2g, ln2b, IMG);
        // 8. FC1 + exact GELU (K=512 static): IMG @ wfc1 -> H1 (bf16)
        gemm_bt<2, 512><<<dim3(16, 128), 512, 0, stream>>>(
            IMG, wfc1T[b], 2048, 512, bfc1, nullptr, nullptr, H1);
        // 9. FC2 (K=2048 RUNTIME, R9 loop): H1 @ wfc2 + bfc2 + XMID
        gemm_bt<1, 0><<<dim3(4, 128), 512, 0, stream>>>(
            H1, wfc2T[b], 512, 2048, bfc2, XMID, (b == 0) ? X1 : XMID, nullptr);
    }
    (void)in_sizes; (void)n_in; (void)out_size; (void)ws_size;
}